// Round 13
// baseline (139.760 us; speedup 1.0000x reference)
//
#include <hip/hip_runtime.h>
#include <math.h>

#define B_   256
#define IN_  512
#define C_   4
#define M_   6
#define K_   64
#define S1_  255
#define S2_  63

#define NBLK1 (C_ * S1_)                 // 1020
#define NBLK2 (C_ * S2_)                 // 252
#define NBLK3 (C_)                       // 4
#define NBLK23 (NBLK2 + NBLK3)           // 256

#define LMIN_ (-6.906754778648554f)
#define LMAX_ ( 6.906754778648554f)
#define LR_   0.001f
#define WCLIP_ 5.0f

typedef float v4f __attribute__((ext_vector_type(4)));

__device__ __forceinline__ float clampf(float v, float lo, float hi) {
    return fminf(fmaxf(v, lo), hi);
}

// One-time prep: xT[i][b], l0[b][i], l0T[i][b]; bias rows of out1/out2.
__global__ __launch_bounds__(256) void prep_kernel(const float* __restrict__ x,
                                                   const float* __restrict__ bias1,
                                                   const float* __restrict__ bias2,
                                                   float* __restrict__ xT,
                                                   float* __restrict__ l0,
                                                   float* __restrict__ l0T,
                                                   float* __restrict__ out1T,
                                                   float* __restrict__ out1RM,
                                                   float* __restrict__ out2T,
                                                   float* __restrict__ out2RM) {
    __shared__ float tx_[32][33];
    __shared__ float tl_[32][33];
    const int i0 = (blockIdx.x & 15) * 32;
    const int b0 = (blockIdx.x >> 4) * 32;
    const int tx = threadIdx.x & 31;
    const int ty = threadIdx.x >> 5;
#pragma unroll
    for (int r = 0; r < 4; ++r) {
        int bb = b0 + ty + 8 * r;
        int ii = i0 + tx;
        float xv = x[(size_t)bb * IN_ + ii];
        float xc = clampf(xv, 0.001f, 0.999f);
        float lv = (ii == 0) ? 0.0f : logf(xc / (1.0f - xc));
        l0[(size_t)bb * IN_ + ii] = lv;
        tx_[ty + 8 * r][tx] = xv;
        tl_[ty + 8 * r][tx] = lv;
    }
    __syncthreads();
#pragma unroll
    for (int r = 0; r < 4; ++r) {
        int ii = i0 + ty + 8 * r;
        int bb = b0 + tx;
        xT[(size_t)ii * B_ + bb]  = tx_[tx][ty + 8 * r];
        l0T[(size_t)ii * B_ + bb] = tl_[tx][ty + 8 * r];
    }
    int gid = blockIdx.x * 256 + threadIdx.x;
    if (gid < C_ * B_) {
        int c = gid >> 8, b = gid & 255;
        float b1 = bias1[c], b2 = bias2[c];
        out1T[((size_t)c * (S1_ + 1)) * B_ + b] = b1;
        out1RM[((size_t)c * B_ + b) * (S1_ + 1)] = b1;
        out2T[((size_t)c * (S2_ + 1)) * B_ + b] = b2;
        out2RM[((size_t)c * B_ + b) * (S2_ + 1)] = b2;
    }
}

// ---- fused dot+fin per tile: 512 threads = 2 k-halves x 256 b ----
// If INLINE_ROUTE, the block first computes its own idx (cmaps dist sign-bits,
// per-half sequential acc + LDS combine -- wl used as scratch).
template<int DIN, bool INLINE_ROUTE>
__device__ __forceinline__ void dotfin_body(
    int tile,
    const float* __restrict__ lgT, long lgT_sc,   // lgT[c*sc + k*B + b]
    const float* __restrict__ w,
    const float* __restrict__ cmaps,   // used if INLINE_ROUTE
    const float* __restrict__ xT,      // used if INLINE_ROUTE
    const int* __restrict__ idx_buf,   // used if !INLINE_ROUTE
    const int* __restrict__ target,
    float* __restrict__ onextT,        // [c][S+1][b]
    float* __restrict__ onextRM,       // [c][b][S+1]
    int* __restrict__ win_g,           // [tiles][K]
    float* __restrict__ dw_g,          // [tiles][K]
    int S,
    float* wl, float* part_s, float* diff_s, int* win_s, int* idx_s)
{
    constexpr int HALF = DIN / 2;
    constexpr int NR   = HALF / 64;
    const int c   = tile / S;
    const int s   = tile - c * S;
    const int tid = threadIdx.x;
    const int kh  = __builtin_amdgcn_readfirstlane(tid >> 8);  // wave-uniform
    const int b   = tid & 255;

    if (tid < K_) win_s[tid] = -1;

    int myrow;
    if (INLINE_ROUTE) {
        // dist over this thread's k-half (sequential acc, round-6 structure)
        const float* cmp = cmaps + (size_t)tile * M_ * IN_;
        float racc[M_];
#pragma unroll
        for (int m = 0; m < M_; ++m) racc[m] = 0.0f;
        const int kw = kh * 256;
        for (int k0 = kw; k0 < kw + 256; k0 += 8) {
            float xv[8];
#pragma unroll
            for (int j = 0; j < 8; ++j) xv[j] = xT[(size_t)(k0 + j) * B_ + b]; // coalesced
#pragma unroll
            for (int j = 0; j < 8; ++j)
#pragma unroll
                for (int m = 0; m < M_; ++m)
                    racc[m] = fmaf(cmp[(size_t)m * IN_ + kw + (k0 - kw) + j], xv[j], racc[m]); // s_load
        }
        if (kh == 1) {
#pragma unroll
            for (int m = 0; m < M_; ++m) wl[m * B_ + b] = racc[m];
        }
        __syncthreads();
        if (kh == 0) {
            int myidx = 0;
#pragma unroll
            for (int m = 0; m < M_; ++m) {
                float t = racc[m] + wl[m * B_ + b];
                myidx |= (t > 0.0f) ? (1 << m) : 0;
            }
            idx_s[b] = myidx;
        }
        __syncthreads();
        myrow = idx_s[b];
    } else {
        myrow = idx_buf[(size_t)tile * B_ + b];
    }

    const float* wp  = w + (size_t)tile * K_ * DIN + kh * HALF;
    float*       dst = wl + kh * (K_ * 65);
    float dot = 0.0f;
#pragma unroll
    for (int r = 0; r < NR; ++r) {
        const float* src = wp + r * 64;
#pragma unroll
        for (int j = 0; j < 4; ++j) {
            int f   = b + 256 * j;
            int row = f >> 4;
            int q   = (f & 15) << 2;
            float4 v = *(const float4*)(src + (size_t)row * DIN + q);
            dst[row * 65 + q + 0] = v.x;
            dst[row * 65 + q + 1] = v.y;
            dst[row * 65 + q + 2] = v.z;
            dst[row * 65 + q + 3] = v.w;
        }
        __syncthreads();
        const float* lgp = lgT + (size_t)c * lgT_sc + (size_t)(kh * HALF + r * 64) * B_ + b;
        const float* wr  = dst + myrow * 65;
        for (int kk = 0; kk < 64; kk += 8) {
            float lv[8];
#pragma unroll
            for (int t = 0; t < 8; ++t) lv[t] = lgp[(size_t)(kk + t) * B_];  // coalesced
#pragma unroll
            for (int t = 0; t < 8; ++t) dot = fmaf(wr[kk + t], lv[t], dot);
        }
        __syncthreads();
    }
    if (kh == 1) part_s[b] = dot;
    __syncthreads();
    if (kh == 0) {
        float total = dot + part_s[b];
        float outv = clampf(total, LMIN_, LMAX_);
        onextT[((size_t)c * (S + 1) + (s + 1)) * B_ + b] = outv;   // coalesced
        onextRM[((size_t)c * B_ + b) * (size_t)(S + 1) + (s + 1)] = outv;
        float tg = (target[b] == c) ? 1.0f : 0.0f;
        diff_s[b] = 1.0f / (1.0f + expf(-outv)) - tg;
        atomicMax(&win_s[myrow], b);       // last-b-wins == max b
    }
    __syncthreads();
    if (tid < K_) {
        int bw = win_s[tid];
        win_g[(size_t)tile * K_ + tid] = bw;
        dw_g[(size_t)tile * K_ + tid]  = (bw >= 0) ? LR_ * diff_s[bw] : 0.0f;
    }
}

// route for layer-2/3 tiles: 1 tile/block, 4 active waves (exact 4-quarter
// pattern of rounds 9-12 -> idx2/idx3 bit-identical). wl used as sacc scratch.
__device__ __forceinline__ void route23_body(
    int rb,
    const float* __restrict__ xT,
    const float* __restrict__ cmaps2,
    const float* __restrict__ cmaps3,
    int* __restrict__ idx23,           // [NBLK23][B]
    float* wl)                         // >= 3*M_*B_ floats
{
    const int tid = threadIdx.x;
    const float* cmp = (rb < NBLK2) ? cmaps2 + (size_t)rb * M_ * IN_
                                    : cmaps3 + (size_t)(rb - NBLK2) * M_ * IN_;
    float acc[4][M_];
    int wv = 0, lane = 0;
    if (tid < 256) {
        wv   = __builtin_amdgcn_readfirstlane(tid >> 6);
        lane = tid & 63;
#pragma unroll
        for (int jb = 0; jb < 4; ++jb)
#pragma unroll
            for (int m = 0; m < M_; ++m) acc[jb][m] = 0.0f;
        const int kw = wv * 128;
        for (int k0 = kw; k0 < kw + 128; k0 += 8) {
            float xv[8][4];
#pragma unroll
            for (int j = 0; j < 8; ++j)
#pragma unroll
                for (int jb = 0; jb < 4; ++jb)
                    xv[j][jb] = xT[(size_t)(k0 + j) * B_ + 64 * jb + lane];
#pragma unroll
            for (int j = 0; j < 8; ++j)
#pragma unroll
                for (int m = 0; m < M_; ++m) {
                    float cv = cmp[(size_t)m * IN_ + k0 + j];
#pragma unroll
                    for (int jb = 0; jb < 4; ++jb)
                        acc[jb][m] = fmaf(cv, xv[j][jb], acc[jb][m]);
                }
        }
        if (wv > 0) {
#pragma unroll
            for (int jb = 0; jb < 4; ++jb)
#pragma unroll
                for (int m = 0; m < M_; ++m)
                    wl[((wv - 1) * M_ + m) * B_ + 64 * jb + lane] = acc[jb][m];
        }
    }
    __syncthreads();
    if (tid < 256 && wv == 0) {
#pragma unroll
        for (int jb = 0; jb < 4; ++jb) {
            int b = 64 * jb + lane;
            int myidx = 0;
#pragma unroll
            for (int m = 0; m < M_; ++m) {
                float t = acc[jb][m] + wl[(0 * M_ + m) * B_ + b]
                                     + wl[(1 * M_ + m) * B_ + b]
                                     + wl[(2 * M_ + m) * B_ + b];
                myidx |= (t > 0.0f) ? (1 << m) : 0;
            }
            idx23[(size_t)rb * B_ + b] = myidx;
        }
    }
}

// fusedL1: blocks [0,NBLK1) = layer-1 dot+fin with inline route;
//          blocks [NBLK1, NBLK1+NBLK23) = route for layers 2/3.
__global__ __launch_bounds__(512) void fusedL1_kernel(
    const float* __restrict__ xT,
    const float* __restrict__ l0T,
    const float* __restrict__ cmaps1,
    const float* __restrict__ cmaps2,
    const float* __restrict__ cmaps3,
    const float* __restrict__ w1,
    const int* __restrict__ target,
    float* __restrict__ out1T, float* __restrict__ out1RM,
    int* __restrict__ win1, float* __restrict__ dw1,
    int* __restrict__ idx23)
{
    __shared__ float wl[2 * K_ * 65];
    __shared__ float part_s[B_];
    __shared__ float diff_s[B_];
    __shared__ int   win_s[K_];
    __shared__ int   idx_s[B_];
    if ((int)blockIdx.x < NBLK1)
        dotfin_body<512, true>(blockIdx.x, l0T, 0L, w1, cmaps1, xT, nullptr, target,
                               out1T, out1RM, win1, dw1, S1_,
                               wl, part_s, diff_s, win_s, idx_s);
    else
        route23_body(blockIdx.x - NBLK1, xT, cmaps2, cmaps3, idx23, wl);
}

// stream update, 512 threads: block -> 2048 float4.
template<int DIN>
__device__ __forceinline__ void update_body(
    int ub,
    const float* __restrict__ w,
    const float* __restrict__ lgRM, long lg_sc,
    const int* __restrict__ win_g,
    const float* __restrict__ dw_g,
    float* __restrict__ nw,
    int SK)
{
    constexpr int QPR = DIN / 4;
    constexpr int QSH = (DIN == 512) ? 7 : 6;
    const int base = ub * 2048 + threadIdx.x;
#pragma unroll
    for (int j = 0; j < 4; ++j) {
        int Q   = base + j * 512;
        int row = Q >> QSH;
        int col = (Q & (QPR - 1)) << 2;
        float4 wv = *(const float4*)(w + (size_t)row * DIN + col);
        int bw = win_g[row];
        if (bw >= 0) {
            float d = dw_g[row];
            int cc  = row / SK;
            const float4 lv = *(const float4*)(lgRM + (size_t)cc * lg_sc + (size_t)bw * DIN + col);
            wv.x = clampf(wv.x - d * lv.x, -WCLIP_, WCLIP_);
            wv.y = clampf(wv.y - d * lv.y, -WCLIP_, WCLIP_);
            wv.z = clampf(wv.z - d * lv.z, -WCLIP_, WCLIP_);
            wv.w = clampf(wv.w - d * lv.w, -WCLIP_, WCLIP_);
        }
        v4f o = {wv.x, wv.y, wv.z, wv.w};
        __builtin_nontemporal_store(o, (v4f*)(nw + (size_t)row * DIN + col));
    }
}

// mix2: first NBLK2 blocks = layer-2 dot+fin; rest = layer-1 update stream.
__global__ __launch_bounds__(512) void mix2_kernel(
    const float* __restrict__ out1T,
    const float* __restrict__ w2,
    const int* __restrict__ idx2,
    const int* __restrict__ target,
    float* __restrict__ out2T, float* __restrict__ out2RM,
    int* __restrict__ win2, float* __restrict__ dw2,
    const float* __restrict__ w1,
    const float* __restrict__ l0,
    const int* __restrict__ win1, const float* __restrict__ dw1,
    float* __restrict__ nw1)
{
    __shared__ float wl[2 * K_ * 65];
    __shared__ float part_s[B_];
    __shared__ float diff_s[B_];
    __shared__ int   win_s[K_];
    __shared__ int   idx_s[B_];
    if ((int)blockIdx.x < NBLK2)
        dotfin_body<256, false>(blockIdx.x, out1T, (long)(S1_ + 1) * B_, w2,
                                nullptr, nullptr, idx2, target,
                                out2T, out2RM, win2, dw2, S2_,
                                wl, part_s, diff_s, win_s, idx_s);
    else
        update_body<512>(blockIdx.x - NBLK2, w1, l0, 0L, win1, dw1, nw1, S1_ * K_);
}

// layer-3 full fusion: dot+fin+update from LDS (w3 read once). 512 threads.
__device__ __forceinline__ void dotfinup3_body(
    int c,
    const float* __restrict__ lgT, long lgT_sc,   // out2T
    const float* __restrict__ lgRM, long lg_sc,   // out2RM
    const float* __restrict__ w3,
    const int* __restrict__ idx3,
    const int* __restrict__ target,
    float* __restrict__ nw3,
    float* __restrict__ logits,
    float* wl /*2*K_*33*/, float* part_s, float* diff_s, float* dw_s, int* win_s)
{
    const int tid = threadIdx.x;
    const int kh  = __builtin_amdgcn_readfirstlane(tid >> 8);
    const int b   = tid & 255;
    if (tid < K_) win_s[tid] = -1;
    const int myrow = idx3[(size_t)c * B_ + b];

    const float* wp  = w3 + (size_t)c * K_ * 64 + kh * 32;
    float*       dst = wl + kh * (K_ * 33);
#pragma unroll
    for (int j = 0; j < 2; ++j) {
        int f   = b + 256 * j;
        int row = f >> 3;
        int q   = (f & 7) << 2;
        float4 v = *(const float4*)(wp + (size_t)row * 64 + q);
        dst[row * 33 + q + 0] = v.x;
        dst[row * 33 + q + 1] = v.y;
        dst[row * 33 + q + 2] = v.z;
        dst[row * 33 + q + 3] = v.w;
    }
    __syncthreads();
    const float* lgp = lgT + (size_t)c * lgT_sc + (size_t)(kh * 32) * B_ + b;
    const float* wr  = dst + myrow * 33;
    float dot = 0.0f;
    for (int kk = 0; kk < 32; kk += 8) {
        float lv[8];
#pragma unroll
        for (int t = 0; t < 8; ++t) lv[t] = lgp[(size_t)(kk + t) * B_];
#pragma unroll
        for (int t = 0; t < 8; ++t) dot = fmaf(wr[kk + t], lv[t], dot);
    }
    if (kh == 1) part_s[b] = dot;
    __syncthreads();
    if (kh == 0) {
        float total = dot + part_s[b];
        float outv = clampf(total, LMIN_, LMAX_);
        logits[(size_t)b * C_ + c] = outv;
        float tg = (target[b] == c) ? 1.0f : 0.0f;
        diff_s[b] = 1.0f / (1.0f + expf(-outv)) - tg;
        atomicMax(&win_s[myrow], b);
    }
    __syncthreads();
    if (tid < K_) dw_s[tid] = (win_s[tid] >= 0) ? LR_ * diff_s[win_s[tid]] : 0.0f;
    __syncthreads();

    const float* lgc = lgRM + (size_t)c * lg_sc;
    float* nwp = nw3 + (size_t)c * K_ * 64;
#pragma unroll
    for (int j = 0; j < 2; ++j) {
        int Q   = tid + 512 * j;
        int row = Q >> 4;
        int col = (Q & 15) << 2;
        const float* wsrc = wl + (col >> 5) * (K_ * 33) + row * 33 + (col & 31);
        float4 wv = {wsrc[0], wsrc[1], wsrc[2], wsrc[3]};
        int bw = win_s[row];
        if (bw >= 0) {
            float d = dw_s[row];
            const float4 lv = *(const float4*)(lgc + (size_t)bw * 64 + col);
            wv.x = clampf(wv.x - d * lv.x, -WCLIP_, WCLIP_);
            wv.y = clampf(wv.y - d * lv.y, -WCLIP_, WCLIP_);
            wv.z = clampf(wv.z - d * lv.z, -WCLIP_, WCLIP_);
            wv.w = clampf(wv.w - d * lv.w, -WCLIP_, WCLIP_);
        }
        v4f o = {wv.x, wv.y, wv.z, wv.w};
        __builtin_nontemporal_store(o, (v4f*)(nwp + (size_t)row * 64 + col));
    }
}

// mix3: first 4 blocks = layer-3 full fusion; rest = layer-2 update stream.
__global__ __launch_bounds__(512) void mix3_kernel(
    const float* __restrict__ out2T,
    const float* __restrict__ out2RM,
    const float* __restrict__ w3,
    const int* __restrict__ idx3,
    const int* __restrict__ target,
    float* __restrict__ nw3,
    float* __restrict__ logits,
    const float* __restrict__ w2,
    const float* __restrict__ out1RM,
    const int* __restrict__ win2, const float* __restrict__ dw2,
    float* __restrict__ nw2)
{
    __shared__ float wl[2 * K_ * 33];
    __shared__ float part_s[B_];
    __shared__ float diff_s[B_];
    __shared__ float dw_s[K_];
    __shared__ int   win_s[K_];
    if ((int)blockIdx.x < NBLK3)
        dotfinup3_body(blockIdx.x, out2T, (long)(S2_ + 1) * B_,
                       out2RM, (long)B_ * (S2_ + 1), w3, idx3, target,
                       nw3, logits, wl, part_s, diff_s, dw_s, win_s);
    else
        update_body<256>(blockIdx.x - NBLK3, w2, out1RM, (long)B_ * (S1_ + 1),
                         win2, dw2, nw2, S2_ * K_);
}

extern "C" void kernel_launch(void* const* d_in, const int* in_sizes, int n_in,
                              void* d_out, int out_size, void* d_ws, size_t ws_size,
                              hipStream_t stream) {
    const float* x      = (const float*)d_in[0];
    const int*   target = (const int*)  d_in[1];
    const float* cmaps1 = (const float*)d_in[2];
    const float* w1     = (const float*)d_in[3];
    const float* bias1  = (const float*)d_in[4];
    const float* cmaps2 = (const float*)d_in[5];
    const float* w2     = (const float*)d_in[6];
    const float* bias2  = (const float*)d_in[7];
    const float* cmaps3 = (const float*)d_in[8];
    const float* w3     = (const float*)d_in[9];
    float* out = (float*)d_out;

    float* xT      = (float*)d_ws;                           // 131072
    float* l0      = xT     + (size_t)IN_ * B_;              // 131072
    float* l0T     = l0     + (size_t)B_ * IN_;              // 131072
    float* out1T   = l0T    + (size_t)IN_ * B_;              // 262144
    float* out1RM  = out1T  + (size_t)C_ * (S1_ + 1) * B_;   // 262144
    float* out2T   = out1RM + (size_t)C_ * B_ * (S1_ + 1);   // 65536
    float* out2RM  = out2T  + (size_t)C_ * (S2_ + 1) * B_;   // 65536
    float* dw_g    = out2RM + (size_t)C_ * B_ * (S2_ + 1);   // (NBLK1+NBLK2)*K
    int*   win_g   = (int*)(dw_g + (size_t)(NBLK1 + NBLK2) * K_);
    int*   idx23   = (int*)(win_g + (size_t)(NBLK1 + NBLK2) * K_);  // NBLK23*B

    float* logits = out;
    float* nw1 = out + (size_t)B_ * C_;
    float* nw2 = nw1 + (size_t)C_ * S1_ * K_ * IN_;
    float* nw3 = nw2 + (size_t)C_ * S2_ * K_ * (S1_ + 1);

    int*   win1 = win_g;                float* dw1 = dw_g;
    int*   win2 = win_g + NBLK1 * K_;   float* dw2 = dw_g + NBLK1 * K_;
    const int* idx2 = idx23;
    const int* idx3 = idx23 + (size_t)NBLK2 * B_;

    prep_kernel<<<dim3(128), dim3(256), 0, stream>>>(
        x, bias1, bias2, xT, l0, l0T, out1T, out1RM, out2T, out2RM);

    // layer-1 dot+fin with inline route  ||  route for layers 2/3
    fusedL1_kernel<<<dim3(NBLK1 + NBLK23), dim3(512), 0, stream>>>(
        xT, l0T, cmaps1, cmaps2, cmaps3, w1, target,
        out1T, out1RM, win1, dw1, idx23);

    // layer-2 dot+fin || layer-1 update stream
    mix2_kernel<<<dim3(NBLK2 + NBLK1 * 4), dim3(512), 0, stream>>>(
        out1T, w2, idx2, target, out2T, out2RM, win2, dw2,
        w1, l0, win1, dw1, nw1);

    // layer-3 dot+fin+update || layer-2 update stream
    mix3_kernel<<<dim3(NBLK3 + NBLK2 * 2), dim3(512), 0, stream>>>(
        out2T, out2RM, w3, idx3, target, nw3, logits,
        w2, out1RM, win2, dw2, nw2);
}

// Round 14
// 131.394 us; speedup vs baseline: 1.0637x; 1.0637x over previous
//
#include <hip/hip_runtime.h>
#include <math.h>

#define B_   256
#define IN_  512
#define C_   4
#define M_   6
#define K_   64
#define S1_  255
#define S2_  63

#define NBLK1 (C_ * S1_)                 // 1020
#define NBLK2 (C_ * S2_)                 // 252
#define NBLK3 (C_)                       // 4
#define NBLK_ALL (NBLK1 + NBLK2 + NBLK3) // 1276

#define LMIN_ (-6.906754778648554f)
#define LMAX_ ( 6.906754778648554f)
#define LR_   0.001f
#define WCLIP_ 5.0f

typedef float v4f __attribute__((ext_vector_type(4)));

__device__ __forceinline__ float clampf(float v, float lo, float hi) {
    return fminf(fmaxf(v, lo), hi);
}

// One-time prep: xT[i][b], l0[b][i], l0T[i][b]; bias rows of out1/out2.
__global__ __launch_bounds__(256) void prep_kernel(const float* __restrict__ x,
                                                   const float* __restrict__ bias1,
                                                   const float* __restrict__ bias2,
                                                   float* __restrict__ xT,
                                                   float* __restrict__ l0,
                                                   float* __restrict__ l0T,
                                                   float* __restrict__ out1T,
                                                   float* __restrict__ out1RM,
                                                   float* __restrict__ out2T,
                                                   float* __restrict__ out2RM) {
    __shared__ float tx_[32][33];
    __shared__ float tl_[32][33];
    const int i0 = (blockIdx.x & 15) * 32;
    const int b0 = (blockIdx.x >> 4) * 32;
    const int tx = threadIdx.x & 31;
    const int ty = threadIdx.x >> 5;
#pragma unroll
    for (int r = 0; r < 4; ++r) {
        int bb = b0 + ty + 8 * r;
        int ii = i0 + tx;
        float xv = x[(size_t)bb * IN_ + ii];
        float xc = clampf(xv, 0.001f, 0.999f);
        float lv = (ii == 0) ? 0.0f : logf(xc / (1.0f - xc));
        l0[(size_t)bb * IN_ + ii] = lv;
        tx_[ty + 8 * r][tx] = xv;
        tl_[ty + 8 * r][tx] = lv;
    }
    __syncthreads();
#pragma unroll
    for (int r = 0; r < 4; ++r) {
        int ii = i0 + ty + 8 * r;
        int bb = b0 + tx;
        xT[(size_t)ii * B_ + bb]  = tx_[tx][ty + 8 * r];
        l0T[(size_t)ii * B_ + bb] = tl_[tx][ty + 8 * r];
    }
    int gid = blockIdx.x * 256 + threadIdx.x;
    if (gid < C_ * B_) {
        int c = gid >> 8, b = gid & 255;
        float b1 = bias1[c], b2 = bias2[c];
        out1T[((size_t)c * (S1_ + 1)) * B_ + b] = b1;
        out1RM[((size_t)c * B_ + b) * (S1_ + 1)] = b1;
        out2T[((size_t)c * (S2_ + 1)) * B_ + b] = b2;
        out2RM[((size_t)c * B_ + b) * (S2_ + 1)] = b2;
    }
}

// Routing: block = 2 tiles, 4 waves split k into 128-wide quarters (proven).
__global__ __launch_bounds__(256) void route_kernel(
    const float* __restrict__ xT,       // [IN][B]
    const float* __restrict__ cmaps1,
    const float* __restrict__ cmaps2,
    const float* __restrict__ cmaps3,
    int* __restrict__ idx_buf)          // [NBLK_ALL][B]
{
    __shared__ float sacc[3][2][M_][B_];   // 36 KB
    const int wv   = __builtin_amdgcn_readfirstlane(threadIdx.x >> 6);
    const int lane = threadIdx.x & 63;
    const int t0   = blockIdx.x * 2;

    const float* cmp[2];
#pragma unroll
    for (int u = 0; u < 2; ++u) {
        int bid = t0 + u;
        if (bid < NBLK1)              cmp[u] = cmaps1 + (size_t)bid * M_ * IN_;
        else if (bid < NBLK1 + NBLK2) cmp[u] = cmaps2 + (size_t)(bid - NBLK1) * M_ * IN_;
        else                          cmp[u] = cmaps3 + (size_t)(bid - NBLK1 - NBLK2) * M_ * IN_;
    }

    float acc[2][4][M_];
#pragma unroll
    for (int u = 0; u < 2; ++u)
#pragma unroll
        for (int jb = 0; jb < 4; ++jb)
#pragma unroll
            for (int m = 0; m < M_; ++m) acc[u][jb][m] = 0.0f;

    const int kw = wv * 128;
    for (int k0 = kw; k0 < kw + 128; k0 += 8) {
        float xv[8][4];
#pragma unroll
        for (int j = 0; j < 8; ++j)
#pragma unroll
            for (int jb = 0; jb < 4; ++jb)
                xv[j][jb] = xT[(size_t)(k0 + j) * B_ + 64 * jb + lane];
#pragma unroll
        for (int j = 0; j < 8; ++j)
#pragma unroll
            for (int u = 0; u < 2; ++u)
#pragma unroll
                for (int m = 0; m < M_; ++m) {
                    float cv = cmp[u][(size_t)m * IN_ + k0 + j];
#pragma unroll
                    for (int jb = 0; jb < 4; ++jb)
                        acc[u][jb][m] = fmaf(cv, xv[j][jb], acc[u][jb][m]);
                }
    }

    if (wv > 0) {
#pragma unroll
        for (int u = 0; u < 2; ++u)
#pragma unroll
            for (int jb = 0; jb < 4; ++jb)
#pragma unroll
                for (int m = 0; m < M_; ++m)
                    sacc[wv - 1][u][m][64 * jb + lane] = acc[u][jb][m];
    }
    __syncthreads();
    if (wv == 0) {
#pragma unroll
        for (int u = 0; u < 2; ++u)
#pragma unroll
            for (int jb = 0; jb < 4; ++jb) {
                int b = 64 * jb + lane;
                int myidx = 0;
#pragma unroll
                for (int m = 0; m < M_; ++m) {
                    float t = acc[u][jb][m] + sacc[0][u][m][b] + sacc[1][u][m][b] + sacc[2][u][m][b];
                    myidx |= (t > 0.0f) ? (1 << m) : 0;
                }
                idx_buf[(size_t)(t0 + u) * B_ + b] = myidx;
            }
    }
}

// ---- fully fused layer: dot + fin + update per tile, 512 threads ----
// 2 k-halves x 256 b for the dot; all 512 stream the update (w re-read is
// L2-hot -- this block just loaded it). win/dw stay in LDS.
template<int DIN>
__device__ __forceinline__ void layerfused_body(
    int tile,
    const float* __restrict__ lgT, long lgT_sc,   // lgT[c*sc + k*B + b]
    const float* __restrict__ lgRM, long lg_sc,   // lg rows for update
    const float* __restrict__ w,
    float* __restrict__ nw,
    const int* __restrict__ idx_buf,
    const int* __restrict__ target,
    float* __restrict__ onextT,        // [c][S+1][b]
    float* __restrict__ onextRM,       // [c][b][S+1]
    int S,
    float* wl, float* part_s, float* diff_s, float* dw_s, int* win_s)
{
    constexpr int HALF = DIN / 2;
    constexpr int NR   = HALF / 64;
    constexpr int QPR  = DIN / 4;
    constexpr int QSH  = (DIN == 512) ? 7 : 6;
    const int c   = tile / S;
    const int s   = tile - c * S;
    const int tid = threadIdx.x;
    const int kh  = __builtin_amdgcn_readfirstlane(tid >> 8);  // wave-uniform
    const int b   = tid & 255;

    if (tid < K_) win_s[tid] = -1;
    const int myrow = idx_buf[(size_t)tile * B_ + b];

    // ---- dot ----
    const float* wp  = w + (size_t)tile * K_ * DIN + kh * HALF;
    float*       dst = wl + kh * (K_ * 65);
    float dot = 0.0f;
#pragma unroll
    for (int r = 0; r < NR; ++r) {
        const float* src = wp + r * 64;
#pragma unroll
        for (int j = 0; j < 4; ++j) {
            int f   = b + 256 * j;
            int row = f >> 4;
            int q   = (f & 15) << 2;
            float4 v = *(const float4*)(src + (size_t)row * DIN + q);
            dst[row * 65 + q + 0] = v.x;
            dst[row * 65 + q + 1] = v.y;
            dst[row * 65 + q + 2] = v.z;
            dst[row * 65 + q + 3] = v.w;
        }
        __syncthreads();
        const float* lgp = lgT + (size_t)c * lgT_sc + (size_t)(kh * HALF + r * 64) * B_ + b;
        const float* wr  = dst + myrow * 65;
        for (int kk = 0; kk < 64; kk += 8) {
            float lv[8];
#pragma unroll
            for (int t = 0; t < 8; ++t) lv[t] = lgp[(size_t)(kk + t) * B_];  // coalesced
#pragma unroll
            for (int t = 0; t < 8; ++t) dot = fmaf(wr[kk + t], lv[t], dot);
        }
        __syncthreads();
    }

    // ---- fin ----
    if (kh == 1) part_s[b] = dot;
    __syncthreads();
    if (kh == 0) {
        float total = dot + part_s[b];
        float outv = clampf(total, LMIN_, LMAX_);
        onextT[((size_t)c * (S + 1) + (s + 1)) * B_ + b] = outv;   // coalesced
        onextRM[((size_t)c * B_ + b) * (size_t)(S + 1) + (s + 1)] = outv;
        float tg = (target[b] == c) ? 1.0f : 0.0f;
        diff_s[b] = 1.0f / (1.0f + expf(-outv)) - tg;
        atomicMax(&win_s[myrow], b);       // last-b-wins == max b
    }
    __syncthreads();
    if (tid < K_) dw_s[tid] = (win_s[tid] >= 0) ? LR_ * diff_s[win_s[tid]] : 0.0f;
    __syncthreads();

    // ---- update: re-read own tile (L2-hot), stream to nw ----
    const float* lgc = lgRM + (size_t)c * lg_sc;
    const float* wp0 = w  + (size_t)tile * K_ * DIN;
    float*       nwp = nw + (size_t)tile * K_ * DIN;
#pragma unroll
    for (int j = 0; j < (K_ * QPR) / 512; ++j) {
        int Q   = tid + 512 * j;
        int row = Q >> QSH;
        int col = (Q & (QPR - 1)) << 2;
        float4 wv = *(const float4*)(wp0 + (size_t)row * DIN + col);
        int bw = win_s[row];
        if (bw >= 0) {
            float d = dw_s[row];
            const float4 lv = *(const float4*)(lgc + (size_t)bw * DIN + col);
            wv.x = clampf(wv.x - d * lv.x, -WCLIP_, WCLIP_);
            wv.y = clampf(wv.y - d * lv.y, -WCLIP_, WCLIP_);
            wv.z = clampf(wv.z - d * lv.z, -WCLIP_, WCLIP_);
            wv.w = clampf(wv.w - d * lv.w, -WCLIP_, WCLIP_);
        }
        v4f o = {wv.x, wv.y, wv.z, wv.w};
        __builtin_nontemporal_store(o, (v4f*)(nwp + (size_t)row * DIN + col));
    }
}

template<int DIN>
__global__ __launch_bounds__(512) void layerfused_kernel(
    const float* __restrict__ lgT, long lgT_sc,
    const float* __restrict__ lgRM, long lg_sc,
    const float* __restrict__ w,
    float* __restrict__ nw,
    const int* __restrict__ idx_buf,
    const int* __restrict__ target,
    float* __restrict__ onextT,
    float* __restrict__ onextRM,
    int S)
{
    __shared__ float wl[2 * K_ * 65];
    __shared__ float part_s[B_];
    __shared__ float diff_s[B_];
    __shared__ float dw_s[K_];
    __shared__ int   win_s[K_];
    layerfused_body<DIN>(blockIdx.x, lgT, lgT_sc, lgRM, lg_sc, w, nw,
                         idx_buf, target, onextT, onextRM, S,
                         wl, part_s, diff_s, dw_s, win_s);
}

// layer-3 full fusion: dot+fin+update from LDS (w3 read once). 512 threads.
__global__ __launch_bounds__(512) void layer3_kernel(
    const float* __restrict__ out2T,
    const float* __restrict__ out2RM,
    const float* __restrict__ w3,
    const int* __restrict__ idx3,
    const int* __restrict__ target,
    float* __restrict__ nw3,
    float* __restrict__ logits)
{
    __shared__ float wl[2 * K_ * 33];
    __shared__ float part_s[B_];
    __shared__ float diff_s[B_];
    __shared__ float dw_s[K_];
    __shared__ int   win_s[K_];
    const int c   = blockIdx.x;
    const int tid = threadIdx.x;
    const int kh  = __builtin_amdgcn_readfirstlane(tid >> 8);
    const int b   = tid & 255;
    if (tid < K_) win_s[tid] = -1;
    const int myrow = idx3[(size_t)c * B_ + b];

    const float* wp  = w3 + (size_t)c * K_ * 64 + kh * 32;
    float*       dst = wl + kh * (K_ * 33);
#pragma unroll
    for (int j = 0; j < 2; ++j) {
        int f   = b + 256 * j;
        int row = f >> 3;
        int q   = (f & 7) << 2;
        float4 v = *(const float4*)(wp + (size_t)row * 64 + q);
        dst[row * 33 + q + 0] = v.x;
        dst[row * 33 + q + 1] = v.y;
        dst[row * 33 + q + 2] = v.z;
        dst[row * 33 + q + 3] = v.w;
    }
    __syncthreads();
    const float* lgp = out2T + (size_t)c * (S2_ + 1) * B_ + (size_t)(kh * 32) * B_ + b;
    const float* wr  = dst + myrow * 33;
    float dot = 0.0f;
    for (int kk = 0; kk < 32; kk += 8) {
        float lv[8];
#pragma unroll
        for (int t = 0; t < 8; ++t) lv[t] = lgp[(size_t)(kk + t) * B_];
#pragma unroll
        for (int t = 0; t < 8; ++t) dot = fmaf(wr[kk + t], lv[t], dot);
    }
    if (kh == 1) part_s[b] = dot;
    __syncthreads();
    if (kh == 0) {
        float total = dot + part_s[b];
        float outv = clampf(total, LMIN_, LMAX_);
        logits[(size_t)b * C_ + c] = outv;
        float tg = (target[b] == c) ? 1.0f : 0.0f;
        diff_s[b] = 1.0f / (1.0f + expf(-outv)) - tg;
        atomicMax(&win_s[myrow], b);
    }
    __syncthreads();
    if (tid < K_) dw_s[tid] = (win_s[tid] >= 0) ? LR_ * diff_s[win_s[tid]] : 0.0f;
    __syncthreads();

    const float* lgc = out2RM + (size_t)c * B_ * (S2_ + 1);
    float* nwp = nw3 + (size_t)c * K_ * 64;
#pragma unroll
    for (int j = 0; j < 2; ++j) {
        int Q   = tid + 512 * j;
        int row = Q >> 4;
        int col = (Q & 15) << 2;
        const float* wsrc = wl + (col >> 5) * (K_ * 33) + row * 33 + (col & 31);
        float4 wv = {wsrc[0], wsrc[1], wsrc[2], wsrc[3]};
        int bw = win_s[row];
        if (bw >= 0) {
            float d = dw_s[row];
            const float4 lv = *(const float4*)(lgc + (size_t)bw * 64 + col);
            wv.x = clampf(wv.x - d * lv.x, -WCLIP_, WCLIP_);
            wv.y = clampf(wv.y - d * lv.y, -WCLIP_, WCLIP_);
            wv.z = clampf(wv.z - d * lv.z, -WCLIP_, WCLIP_);
            wv.w = clampf(wv.w - d * lv.w, -WCLIP_, WCLIP_);
        }
        v4f o = {wv.x, wv.y, wv.z, wv.w};
        __builtin_nontemporal_store(o, (v4f*)(nwp + (size_t)row * 64 + col));
    }
}

extern "C" void kernel_launch(void* const* d_in, const int* in_sizes, int n_in,
                              void* d_out, int out_size, void* d_ws, size_t ws_size,
                              hipStream_t stream) {
    const float* x      = (const float*)d_in[0];
    const int*   target = (const int*)  d_in[1];
    const float* cmaps1 = (const float*)d_in[2];
    const float* w1     = (const float*)d_in[3];
    const float* bias1  = (const float*)d_in[4];
    const float* cmaps2 = (const float*)d_in[5];
    const float* w2     = (const float*)d_in[6];
    const float* bias2  = (const float*)d_in[7];
    const float* cmaps3 = (const float*)d_in[8];
    const float* w3     = (const float*)d_in[9];
    float* out = (float*)d_out;

    float* xT      = (float*)d_ws;                           // 131072
    float* l0      = xT     + (size_t)IN_ * B_;              // 131072
    float* l0T     = l0     + (size_t)B_ * IN_;              // 131072
    float* out1T   = l0T    + (size_t)IN_ * B_;              // 262144
    float* out1RM  = out1T  + (size_t)C_ * (S1_ + 1) * B_;   // 262144
    float* out2T   = out1RM + (size_t)C_ * B_ * (S1_ + 1);   // 65536
    float* out2RM  = out2T  + (size_t)C_ * (S2_ + 1) * B_;   // 65536
    int*   idx_buf = (int*)(out2RM + (size_t)C_ * B_ * (S2_ + 1));  // NBLK_ALL*B

    float* logits = out;
    float* nw1 = out + (size_t)B_ * C_;
    float* nw2 = nw1 + (size_t)C_ * S1_ * K_ * IN_;
    float* nw3 = nw2 + (size_t)C_ * S2_ * K_ * (S1_ + 1);

    const int* idx1 = idx_buf;
    const int* idx2 = idx_buf + (size_t)NBLK1 * B_;
    const int* idx3 = idx_buf + (size_t)(NBLK1 + NBLK2) * B_;

    prep_kernel<<<dim3(128), dim3(256), 0, stream>>>(
        x, bias1, bias2, xT, l0, l0T, out1T, out1RM, out2T, out2RM);

    route_kernel<<<dim3(NBLK_ALL / 2), dim3(256), 0, stream>>>(
        xT, cmaps1, cmaps2, cmaps3, idx_buf);

    // layer 1: dot+fin+update fused per tile
    layerfused_kernel<512><<<dim3(NBLK1), dim3(512), 0, stream>>>(
        l0T, 0L, l0, 0L, w1, nw1, idx1, target, out1T, out1RM, S1_);

    // layer 2
    layerfused_kernel<256><<<dim3(NBLK2), dim3(512), 0, stream>>>(
        out1T, (long)(S1_ + 1) * B_, out1RM, (long)B_ * (S1_ + 1),
        w2, nw2, idx2, target, out2T, out2RM, S2_);

    // layer 3
    layer3_kernel<<<dim3(NBLK3), dim3(512), 0, stream>>>(
        out2T, out2RM, w3, idx3, target, nw3, logits);
}

// Round 15
// 125.285 us; speedup vs baseline: 1.1155x; 1.0488x over previous
//
#include <hip/hip_runtime.h>
#include <math.h>

#define B_   256
#define IN_  512
#define C_   4
#define M_   6
#define K_   64
#define S1_  255
#define S2_  63

#define NBLK1 (C_ * S1_)                 // 1020
#define NBLK2 (C_ * S2_)                 // 252
#define NBLK3 (C_)                       // 4
#define NBLK_ALL (NBLK1 + NBLK2 + NBLK3) // 1276

#define LMIN_ (-6.906754778648554f)
#define LMAX_ ( 6.906754778648554f)
#define LR_   0.001f
#define WCLIP_ 5.0f

typedef float v4f __attribute__((ext_vector_type(4)));

__device__ __forceinline__ float clampf(float v, float lo, float hi) {
    return fminf(fmaxf(v, lo), hi);
}

// One-time prep: xT[i][b], l0[b][i], l0T[i][b]; bias rows of out1/out2.
__global__ __launch_bounds__(256) void prep_kernel(const float* __restrict__ x,
                                                   const float* __restrict__ bias1,
                                                   const float* __restrict__ bias2,
                                                   float* __restrict__ xT,
                                                   float* __restrict__ l0,
                                                   float* __restrict__ l0T,
                                                   float* __restrict__ out1T,
                                                   float* __restrict__ out1RM,
                                                   float* __restrict__ out2T,
                                                   float* __restrict__ out2RM) {
    __shared__ float tx_[32][33];
    __shared__ float tl_[32][33];
    const int i0 = (blockIdx.x & 15) * 32;
    const int b0 = (blockIdx.x >> 4) * 32;
    const int tx = threadIdx.x & 31;
    const int ty = threadIdx.x >> 5;
#pragma unroll
    for (int r = 0; r < 4; ++r) {
        int bb = b0 + ty + 8 * r;
        int ii = i0 + tx;
        float xv = x[(size_t)bb * IN_ + ii];
        float xc = clampf(xv, 0.001f, 0.999f);
        float lv = (ii == 0) ? 0.0f : logf(xc / (1.0f - xc));
        l0[(size_t)bb * IN_ + ii] = lv;
        tx_[ty + 8 * r][tx] = xv;
        tl_[ty + 8 * r][tx] = lv;
    }
    __syncthreads();
#pragma unroll
    for (int r = 0; r < 4; ++r) {
        int ii = i0 + ty + 8 * r;
        int bb = b0 + tx;
        xT[(size_t)ii * B_ + bb]  = tx_[tx][ty + 8 * r];
        l0T[(size_t)ii * B_ + bb] = tl_[tx][ty + 8 * r];
    }
    int gid = blockIdx.x * 256 + threadIdx.x;
    if (gid < C_ * B_) {
        int c = gid >> 8, b = gid & 255;
        float b1 = bias1[c], b2 = bias2[c];
        out1T[((size_t)c * (S1_ + 1)) * B_ + b] = b1;
        out1RM[((size_t)c * B_ + b) * (S1_ + 1)] = b1;
        out2T[((size_t)c * (S2_ + 1)) * B_ + b] = b2;
        out2RM[((size_t)c * B_ + b) * (S2_ + 1)] = b2;
    }
}

// Routing: block = 2 tiles, 4 waves split k into 128-wide quarters (proven).
__global__ __launch_bounds__(256) void route_kernel(
    const float* __restrict__ xT,       // [IN][B]
    const float* __restrict__ cmaps1,
    const float* __restrict__ cmaps2,
    const float* __restrict__ cmaps3,
    int* __restrict__ idx_buf)          // [NBLK_ALL][B]
{
    __shared__ float sacc[3][2][M_][B_];   // 36 KB
    const int wv   = __builtin_amdgcn_readfirstlane(threadIdx.x >> 6);
    const int lane = threadIdx.x & 63;
    const int t0   = blockIdx.x * 2;

    const float* cmp[2];
#pragma unroll
    for (int u = 0; u < 2; ++u) {
        int bid = t0 + u;
        if (bid < NBLK1)              cmp[u] = cmaps1 + (size_t)bid * M_ * IN_;
        else if (bid < NBLK1 + NBLK2) cmp[u] = cmaps2 + (size_t)(bid - NBLK1) * M_ * IN_;
        else                          cmp[u] = cmaps3 + (size_t)(bid - NBLK1 - NBLK2) * M_ * IN_;
    }

    float acc[2][4][M_];
#pragma unroll
    for (int u = 0; u < 2; ++u)
#pragma unroll
        for (int jb = 0; jb < 4; ++jb)
#pragma unroll
            for (int m = 0; m < M_; ++m) acc[u][jb][m] = 0.0f;

    const int kw = wv * 128;
    for (int k0 = kw; k0 < kw + 128; k0 += 8) {
        float xv[8][4];
#pragma unroll
        for (int j = 0; j < 8; ++j)
#pragma unroll
            for (int jb = 0; jb < 4; ++jb)
                xv[j][jb] = xT[(size_t)(k0 + j) * B_ + 64 * jb + lane];
#pragma unroll
        for (int j = 0; j < 8; ++j)
#pragma unroll
            for (int u = 0; u < 2; ++u)
#pragma unroll
                for (int m = 0; m < M_; ++m) {
                    float cv = cmp[u][(size_t)m * IN_ + k0 + j];
#pragma unroll
                    for (int jb = 0; jb < 4; ++jb)
                        acc[u][jb][m] = fmaf(cv, xv[j][jb], acc[u][jb][m]);
                }
    }

    if (wv > 0) {
#pragma unroll
        for (int u = 0; u < 2; ++u)
#pragma unroll
            for (int jb = 0; jb < 4; ++jb)
#pragma unroll
                for (int m = 0; m < M_; ++m)
                    sacc[wv - 1][u][m][64 * jb + lane] = acc[u][jb][m];
    }
    __syncthreads();
    if (wv == 0) {
#pragma unroll
        for (int u = 0; u < 2; ++u)
#pragma unroll
            for (int jb = 0; jb < 4; ++jb) {
                int b = 64 * jb + lane;
                int myidx = 0;
#pragma unroll
                for (int m = 0; m < M_; ++m) {
                    float t = acc[u][jb][m] + sacc[0][u][m][b] + sacc[1][u][m][b] + sacc[2][u][m][b];
                    myidx |= (t > 0.0f) ? (1 << m) : 0;
                }
                idx_buf[(size_t)(t0 + u) * B_ + b] = myidx;
            }
    }
}

// ---- fused dot+fin per tile: 512 threads = 2 k-halves x 256 b ----
// Staging uses register-prefetch double buffering: slice r+1's global loads
// are issued before round r's FMA phase -> HBM read stream stays continuous.
template<int DIN>
__device__ __forceinline__ void dotfin_body(
    int tile,
    const float* __restrict__ lgT, long lgT_sc,   // lgT[c*sc + k*B + b]
    const float* __restrict__ w,
    const int* __restrict__ idx_buf,
    const int* __restrict__ target,
    float* __restrict__ onextT,        // [c][S+1][b]
    float* __restrict__ onextRM,       // [c][b][S+1]
    int* __restrict__ win_g,           // [tiles][K]
    float* __restrict__ dw_g,          // [tiles][K]
    int S,
    float* wl, float* part_s, float* diff_s, int* win_s)
{
    constexpr int HALF = DIN / 2;
    constexpr int NR   = HALF / 64;
    const int c   = tile / S;
    const int s   = tile - c * S;
    const int tid = threadIdx.x;
    const int kh  = __builtin_amdgcn_readfirstlane(tid >> 8);  // wave-uniform
    const int b   = tid & 255;

    if (tid < K_) win_s[tid] = -1;
    const int myrow = idx_buf[(size_t)tile * B_ + b];

    const float* wp  = w + (size_t)tile * K_ * DIN + kh * HALF;
    float*       dst = wl + kh * (K_ * 65);

    int rrow[4], rq[4];
    float4 pre[4];
#pragma unroll
    for (int j = 0; j < 4; ++j) {
        int f   = b + 256 * j;
        rrow[j] = f >> 4;
        rq[j]   = (f & 15) << 2;
        pre[j]  = *(const float4*)(wp + (size_t)rrow[j] * DIN + rq[j]);
    }

    float dot = 0.0f;
#pragma unroll
    for (int r = 0; r < NR; ++r) {
#pragma unroll
        for (int j = 0; j < 4; ++j) {
            dst[rrow[j] * 65 + rq[j] + 0] = pre[j].x;
            dst[rrow[j] * 65 + rq[j] + 1] = pre[j].y;
            dst[rrow[j] * 65 + rq[j] + 2] = pre[j].z;
            dst[rrow[j] * 65 + rq[j] + 3] = pre[j].w;
        }
        if (r + 1 < NR) {                 // prefetch next slice (in flight
            const float* src = wp + (r + 1) * 64;     //  during FMA phase)
#pragma unroll
            for (int j = 0; j < 4; ++j)
                pre[j] = *(const float4*)(src + (size_t)rrow[j] * DIN + rq[j]);
        }
        __syncthreads();
        const float* lgp = lgT + (size_t)c * lgT_sc + (size_t)(kh * HALF + r * 64) * B_ + b;
        const float* wr  = dst + myrow * 65;
        for (int kk = 0; kk < 64; kk += 8) {
            float lv[8];
#pragma unroll
            for (int t = 0; t < 8; ++t) lv[t] = lgp[(size_t)(kk + t) * B_];  // coalesced
#pragma unroll
            for (int t = 0; t < 8; ++t) dot = fmaf(wr[kk + t], lv[t], dot);
        }
        __syncthreads();
    }
    if (kh == 1) part_s[b] = dot;
    __syncthreads();
    if (kh == 0) {
        float total = dot + part_s[b];
        float outv = clampf(total, LMIN_, LMAX_);
        onextT[((size_t)c * (S + 1) + (s + 1)) * B_ + b] = outv;   // coalesced
        onextRM[((size_t)c * B_ + b) * (size_t)(S + 1) + (s + 1)] = outv;
        float tg = (target[b] == c) ? 1.0f : 0.0f;
        diff_s[b] = 1.0f / (1.0f + expf(-outv)) - tg;
        atomicMax(&win_s[myrow], b);       // last-b-wins == max b
    }
    __syncthreads();
    if (tid < K_) {
        int bw = win_s[tid];
        win_g[(size_t)tile * K_ + tid] = bw;
        dw_g[(size_t)tile * K_ + tid]  = (bw >= 0) ? LR_ * diff_s[bw] : 0.0f;
    }
}

// stream update, 512 threads: block -> 2048 float4. Batched loads (all w,
// then all win/dw, then all lg) so the MLP isn't serialized by dependences.
template<int DIN>
__device__ __forceinline__ void update_body(
    int ub,
    const float* __restrict__ w,
    const float* __restrict__ lgRM, long lg_sc,
    const int* __restrict__ win_g,
    const float* __restrict__ dw_g,
    float* __restrict__ nw,
    int SK)
{
    constexpr int QPR = DIN / 4;
    constexpr int QSH = (DIN == 512) ? 7 : 6;
    const int base = ub * 2048 + threadIdx.x;
    int row[4], col[4], bw[4];
    float d[4];
    float4 wv[4], lv[4];
#pragma unroll
    for (int j = 0; j < 4; ++j) {
        int Q  = base + j * 512;
        row[j] = Q >> QSH;
        col[j] = (Q & (QPR - 1)) << 2;
        wv[j]  = *(const float4*)(w + (size_t)row[j] * DIN + col[j]);
    }
#pragma unroll
    for (int j = 0; j < 4; ++j) {
        bw[j] = win_g[row[j]];
        d[j]  = dw_g[row[j]];
    }
#pragma unroll
    for (int j = 0; j < 4; ++j) {
        int safe = bw[j] < 0 ? 0 : bw[j];
        int cc   = row[j] / SK;
        lv[j] = *(const float4*)(lgRM + (size_t)cc * lg_sc + (size_t)safe * DIN + col[j]);
    }
#pragma unroll
    for (int j = 0; j < 4; ++j) {
        if (bw[j] >= 0) {
            wv[j].x = clampf(wv[j].x - d[j] * lv[j].x, -WCLIP_, WCLIP_);
            wv[j].y = clampf(wv[j].y - d[j] * lv[j].y, -WCLIP_, WCLIP_);
            wv[j].z = clampf(wv[j].z - d[j] * lv[j].z, -WCLIP_, WCLIP_);
            wv[j].w = clampf(wv[j].w - d[j] * lv[j].w, -WCLIP_, WCLIP_);
        }
        v4f o = {wv[j].x, wv[j].y, wv[j].z, wv[j].w};
        __builtin_nontemporal_store(o, (v4f*)(nw + (size_t)row[j] * DIN + col[j]));
    }
}

// Layer-1 dot+fin standalone.
__global__ __launch_bounds__(512) void dotfin1_kernel(
    const float* __restrict__ l0T,
    const float* __restrict__ w1,
    const int* __restrict__ idx1,
    const int* __restrict__ target,
    float* __restrict__ out1T, float* __restrict__ out1RM,
    int* __restrict__ win1, float* __restrict__ dw1)
{
    __shared__ float wl[2 * K_ * 65];
    __shared__ float part_s[B_];
    __shared__ float diff_s[B_];
    __shared__ int   win_s[K_];
    dotfin_body<512>(blockIdx.x, l0T, 0L, w1, idx1, target,
                     out1T, out1RM, win1, dw1, S1_, wl, part_s, diff_s, win_s);
}

// mix2: first NBLK2 blocks = layer-2 dot+fin; rest = layer-1 update stream.
__global__ __launch_bounds__(512) void mix2_kernel(
    const float* __restrict__ out1T,
    const float* __restrict__ w2,
    const int* __restrict__ idx2,
    const int* __restrict__ target,
    float* __restrict__ out2T, float* __restrict__ out2RM,
    int* __restrict__ win2, float* __restrict__ dw2,
    const float* __restrict__ w1,
    const float* __restrict__ l0,
    const int* __restrict__ win1, const float* __restrict__ dw1,
    float* __restrict__ nw1)
{
    __shared__ float wl[2 * K_ * 65];
    __shared__ float part_s[B_];
    __shared__ float diff_s[B_];
    __shared__ int   win_s[K_];
    if ((int)blockIdx.x < NBLK2)
        dotfin_body<256>(blockIdx.x, out1T, (long)(S1_ + 1) * B_, w2, idx2, target,
                         out2T, out2RM, win2, dw2, S2_,
                         wl, part_s, diff_s, win_s);
    else
        update_body<512>(blockIdx.x - NBLK2, w1, l0, 0L, win1, dw1, nw1, S1_ * K_);
}

// layer-3 full fusion: dot+fin+update from LDS (w3 read once). 512 threads.
__device__ __forceinline__ void dotfinup3_body(
    int c,
    const float* __restrict__ lgT, long lgT_sc,   // out2T
    const float* __restrict__ lgRM, long lg_sc,   // out2RM
    const float* __restrict__ w3,
    const int* __restrict__ idx3,
    const int* __restrict__ target,
    float* __restrict__ nw3,
    float* __restrict__ logits,
    float* wl /*2*K_*33*/, float* part_s, float* diff_s, float* dw_s, int* win_s)
{
    const int tid = threadIdx.x;
    const int kh  = __builtin_amdgcn_readfirstlane(tid >> 8);
    const int b   = tid & 255;
    if (tid < K_) win_s[tid] = -1;
    const int myrow = idx3[(size_t)c * B_ + b];

    const float* wp  = w3 + (size_t)c * K_ * 64 + kh * 32;
    float*       dst = wl + kh * (K_ * 33);
#pragma unroll
    for (int j = 0; j < 2; ++j) {
        int f   = b + 256 * j;
        int row = f >> 3;
        int q   = (f & 7) << 2;
        float4 v = *(const float4*)(wp + (size_t)row * 64 + q);
        dst[row * 33 + q + 0] = v.x;
        dst[row * 33 + q + 1] = v.y;
        dst[row * 33 + q + 2] = v.z;
        dst[row * 33 + q + 3] = v.w;
    }
    __syncthreads();
    const float* lgp = lgT + (size_t)c * lgT_sc + (size_t)(kh * 32) * B_ + b;
    const float* wr  = dst + myrow * 33;
    float dot = 0.0f;
    for (int kk = 0; kk < 32; kk += 8) {
        float lv[8];
#pragma unroll
        for (int t = 0; t < 8; ++t) lv[t] = lgp[(size_t)(kk + t) * B_];
#pragma unroll
        for (int t = 0; t < 8; ++t) dot = fmaf(wr[kk + t], lv[t], dot);
    }
    if (kh == 1) part_s[b] = dot;
    __syncthreads();
    if (kh == 0) {
        float total = dot + part_s[b];
        float outv = clampf(total, LMIN_, LMAX_);
        logits[(size_t)b * C_ + c] = outv;
        float tg = (target[b] == c) ? 1.0f : 0.0f;
        diff_s[b] = 1.0f / (1.0f + expf(-outv)) - tg;
        atomicMax(&win_s[myrow], b);
    }
    __syncthreads();
    if (tid < K_) dw_s[tid] = (win_s[tid] >= 0) ? LR_ * diff_s[win_s[tid]] : 0.0f;
    __syncthreads();

    const float* lgc = lgRM + (size_t)c * lg_sc;
    float* nwp = nw3 + (size_t)c * K_ * 64;
#pragma unroll
    for (int j = 0; j < 2; ++j) {
        int Q   = tid + 512 * j;
        int row = Q >> 4;
        int col = (Q & 15) << 2;
        const float* wsrc = wl + (col >> 5) * (K_ * 33) + row * 33 + (col & 31);
        float4 wv = {wsrc[0], wsrc[1], wsrc[2], wsrc[3]};
        int bw = win_s[row];
        if (bw >= 0) {
            float d = dw_s[row];
            const float4 lv = *(const float4*)(lgc + (size_t)bw * 64 + col);
            wv.x = clampf(wv.x - d * lv.x, -WCLIP_, WCLIP_);
            wv.y = clampf(wv.y - d * lv.y, -WCLIP_, WCLIP_);
            wv.z = clampf(wv.z - d * lv.z, -WCLIP_, WCLIP_);
            wv.w = clampf(wv.w - d * lv.w, -WCLIP_, WCLIP_);
        }
        v4f o = {wv.x, wv.y, wv.z, wv.w};
        __builtin_nontemporal_store(o, (v4f*)(nwp + (size_t)row * 64 + col));
    }
}

// mix3: first 4 blocks = layer-3 full fusion; rest = layer-2 update stream.
__global__ __launch_bounds__(512) void mix3_kernel(
    const float* __restrict__ out2T,
    const float* __restrict__ out2RM,
    const float* __restrict__ w3,
    const int* __restrict__ idx3,
    const int* __restrict__ target,
    float* __restrict__ nw3,
    float* __restrict__ logits,
    const float* __restrict__ w2,
    const float* __restrict__ out1RM,
    const int* __restrict__ win2, const float* __restrict__ dw2,
    float* __restrict__ nw2)
{
    __shared__ float wl[2 * K_ * 33];
    __shared__ float part_s[B_];
    __shared__ float diff_s[B_];
    __shared__ float dw_s[K_];
    __shared__ int   win_s[K_];
    if ((int)blockIdx.x < NBLK3)
        dotfinup3_body(blockIdx.x, out2T, (long)(S2_ + 1) * B_,
                       out2RM, (long)B_ * (S2_ + 1), w3, idx3, target,
                       nw3, logits, wl, part_s, diff_s, dw_s, win_s);
    else
        update_body<256>(blockIdx.x - NBLK3, w2, out1RM, (long)B_ * (S1_ + 1),
                         win2, dw2, nw2, S2_ * K_);
}

extern "C" void kernel_launch(void* const* d_in, const int* in_sizes, int n_in,
                              void* d_out, int out_size, void* d_ws, size_t ws_size,
                              hipStream_t stream) {
    const float* x      = (const float*)d_in[0];
    const int*   target = (const int*)  d_in[1];
    const float* cmaps1 = (const float*)d_in[2];
    const float* w1     = (const float*)d_in[3];
    const float* bias1  = (const float*)d_in[4];
    const float* cmaps2 = (const float*)d_in[5];
    const float* w2     = (const float*)d_in[6];
    const float* bias2  = (const float*)d_in[7];
    const float* cmaps3 = (const float*)d_in[8];
    const float* w3     = (const float*)d_in[9];
    float* out = (float*)d_out;

    float* xT      = (float*)d_ws;                           // 131072
    float* l0      = xT     + (size_t)IN_ * B_;              // 131072
    float* l0T     = l0     + (size_t)B_ * IN_;              // 131072
    float* out1T   = l0T    + (size_t)IN_ * B_;              // 262144
    float* out1RM  = out1T  + (size_t)C_ * (S1_ + 1) * B_;   // 262144
    float* out2T   = out1RM + (size_t)C_ * B_ * (S1_ + 1);   // 65536
    float* out2RM  = out2T  + (size_t)C_ * (S2_ + 1) * B_;   // 65536
    float* dw_g    = out2RM + (size_t)C_ * B_ * (S2_ + 1);   // (NBLK1+NBLK2)*K
    int*   win_g   = (int*)(dw_g + (size_t)(NBLK1 + NBLK2) * K_);
    int*   idx_buf = (int*)(win_g + (size_t)(NBLK1 + NBLK2) * K_);  // NBLK_ALL*B

    float* logits = out;
    float* nw1 = out + (size_t)B_ * C_;
    float* nw2 = nw1 + (size_t)C_ * S1_ * K_ * IN_;
    float* nw3 = nw2 + (size_t)C_ * S2_ * K_ * (S1_ + 1);

    int*   win1 = win_g;                float* dw1 = dw_g;
    int*   win2 = win_g + NBLK1 * K_;   float* dw2 = dw_g + NBLK1 * K_;
    const int* idx1 = idx_buf;
    const int* idx2 = idx_buf + (size_t)NBLK1 * B_;
    const int* idx3 = idx_buf + (size_t)(NBLK1 + NBLK2) * B_;

    prep_kernel<<<dim3(128), dim3(256), 0, stream>>>(
        x, bias1, bias2, xT, l0, l0T, out1T, out1RM, out2T, out2RM);

    route_kernel<<<dim3(NBLK_ALL / 2), dim3(256), 0, stream>>>(
        xT, cmaps1, cmaps2, cmaps3, idx_buf);

    // layer-1 dot+fin (per-tile, prefetch double-buffered staging)
    dotfin1_kernel<<<dim3(NBLK1), dim3(512), 0, stream>>>(
        l0T, w1, idx1, target, out1T, out1RM, win1, dw1);

    // layer-2 dot+fin || layer-1 update stream
    mix2_kernel<<<dim3(NBLK2 + NBLK1 * 4), dim3(512), 0, stream>>>(
        out1T, w2, idx2, target, out2T, out2RM, win2, dw2,
        w1, l0, win1, dw1, nw1);

    // layer-3 dot+fin+update || layer-2 update stream
    mix3_kernel<<<dim3(NBLK3 + NBLK2 * 2), dim3(512), 0, stream>>>(
        out2T, out2RM, w3, idx3, target, nw3, logits,
        w2, out1RM, win2, dw2, nw2);
}